// Round 1
// baseline (39.878 us; speedup 1.0000x reference)
//
#include <hip/hip_runtime.h>

#ifndef NUM_CLASSES
#define NUM_CLASSES 10
#endif

// Problem constants (from reference setup_inputs):
//   x: (B=64, TS=128, C=1, H=64, W=64) fp32  -> K = C*H*W = 4096
//   Wfc: (10, 4096) fp32, bfc: (10,) fp32
//   out: (64, 10) fp32 = (Wfc @ S^T scaled) per derivation in header comment.
constexpr int B_       = 64;
constexpr int TS_      = 128;
constexpr int K_       = 4096;
constexpr int THREADS_ = 256;
constexpr int KV_      = 4;                       // floats per thread (float4)
constexpr int KGROUPS_ = K_ / (KV_ * THREADS_);   // 4
constexpr int TCHUNKS_ = 2;

// Kernel 1: S[tc][b][k] = sum over t-chunk of sign3(x[b,t,k] - x[b,t-1,k])
// Grid: (KGROUPS_, B_, TCHUNKS_), block: THREADS_
__global__ __launch_bounds__(THREADS_) void sign_sum_kernel(
    const float* __restrict__ x, int* __restrict__ S)
{
    const int kg = blockIdx.x;
    const int b  = blockIdx.y;
    const int tc = blockIdx.z;

    const int k0 = (kg * THREADS_ + threadIdx.x) * KV_;

    // chunk tc covers diffs t in [t_begin+1, t_end]; reads frames t_begin..t_end
    const int t_begin = tc * (TS_ / TCHUNKS_);
    const int t_end   = (tc == TCHUNKS_ - 1) ? (TS_ - 1) : ((tc + 1) * (TS_ / TCHUNKS_));

    const float* xp = x + ((size_t)b * TS_ + t_begin) * K_ + k0;
    float4 prev = *reinterpret_cast<const float4*>(xp);

    int s0 = 0, s1 = 0, s2 = 0, s3 = 0;

#pragma unroll 4
    for (int t = t_begin + 1; t <= t_end; ++t) {
        xp += K_;
        const float4 cur = *reinterpret_cast<const float4*>(xp);
        float d;
        d = cur.x - prev.x; s0 += (d > 0.0f) - (d < 0.0f);
        d = cur.y - prev.y; s1 += (d > 0.0f) - (d < 0.0f);
        d = cur.z - prev.z; s2 += (d > 0.0f) - (d < 0.0f);
        d = cur.w - prev.w; s3 += (d > 0.0f) - (d < 0.0f);
        prev = cur;
    }

    int4* Sp = reinterpret_cast<int4*>(S + ((size_t)tc * B_ + b) * K_ + k0);
    *Sp = make_int4(s0, s1, s2, s3);
}

// Kernel 2: out[b][c] = (sum_k (S0+S1)[b][k] * Wfc[c][k] + (TS-1)*bfc[c]) / TS
// Grid: B_, block: THREADS_. Fixed-order reduction -> deterministic.
__global__ __launch_bounds__(THREADS_) void fc_reduce_kernel(
    const int* __restrict__ S, const float* __restrict__ Wfc,
    const float* __restrict__ bfc, float* __restrict__ out)
{
    const int b   = blockIdx.x;
    const int tid = threadIdx.x;

    float acc[NUM_CLASSES];
#pragma unroll
    for (int c = 0; c < NUM_CLASSES; ++c) acc[c] = 0.0f;

    const int* S0 = S + (size_t)b * K_;
    const int* S1 = S + ((size_t)B_ + b) * K_;

    for (int k = tid * KV_; k < K_; k += THREADS_ * KV_) {
        const int4 a0 = *reinterpret_cast<const int4*>(S0 + k);
        const int4 a1 = *reinterpret_cast<const int4*>(S1 + k);
        const float sx = (float)(a0.x + a1.x);
        const float sy = (float)(a0.y + a1.y);
        const float sz = (float)(a0.z + a1.z);
        const float sw = (float)(a0.w + a1.w);
#pragma unroll
        for (int c = 0; c < NUM_CLASSES; ++c) {
            const float4 w = *reinterpret_cast<const float4*>(Wfc + (size_t)c * K_ + k);
            acc[c] += sx * w.x + sy * w.y + sz * w.z + sw * w.w;
        }
    }

    __shared__ float red[NUM_CLASSES][THREADS_];
#pragma unroll
    for (int c = 0; c < NUM_CLASSES; ++c) red[c][tid] = acc[c];
    __syncthreads();

    for (int stride = THREADS_ / 2; stride > 0; stride >>= 1) {
        if (tid < stride) {
#pragma unroll
            for (int c = 0; c < NUM_CLASSES; ++c) red[c][tid] += red[c][tid + stride];
        }
        __syncthreads();
    }

    if (tid < NUM_CLASSES) {
        out[b * NUM_CLASSES + tid] =
            (red[tid][0] + (float)(TS_ - 1) * bfc[tid]) * (1.0f / (float)TS_);
    }
}

extern "C" void kernel_launch(void* const* d_in, const int* in_sizes, int n_in,
                              void* d_out, int out_size, void* d_ws, size_t ws_size,
                              hipStream_t stream)
{
    const float* x   = (const float*)d_in[0];
    const float* Wfc = (const float*)d_in[1];
    const float* bfc = (const float*)d_in[2];
    float* out = (float*)d_out;
    int* S = (int*)d_ws;   // needs TCHUNKS_*B_*K_*4 = 2 MiB

    dim3 grid1(KGROUPS_, B_, TCHUNKS_);
    sign_sum_kernel<<<grid1, THREADS_, 0, stream>>>(x, S);

    fc_reduce_kernel<<<B_, THREADS_, 0, stream>>>(S, Wfc, bfc, out);
}